// Round 9
// baseline (154.059 us; speedup 1.0000x reference)
//
#include <hip/hip_runtime.h>
#include <cmath>
#include <complex>

// ChebyDecimate: 8th-order Chebyshev-I lowpass (4 cascaded biquads, DF2T,
// zero init state) + decimate-by-2.  x: [32, 131072] f32 -> out: [32, 65536] f32.
//
// v4 = v3 kernel UNCHANGED, launched 8x back-to-back as a timing diagnostic:
// dur_us(8x) = fixed_harness + 8*k  =>  k = (dur_8x - 71.5)/7.
// v3: overlap-save, H=128, 4 sections software-pipelined across samples,
// LDS-staged coalesced I/O (XOR-swizzled).

#define T_LEN   131072
#define B_ROWS  32
#define OUT_LEN (T_LEN / 2)
#define L_CHUNK 64
#define H_WARM  128
#define TPB     256
#define BLOCKS_PER_ROW (T_LEN / (L_CHUNK * TPB))      /* 8 */
#define WIN_FLOATS (TPB * L_CHUNK + H_WARM)           /* 16512 */
#define WIN_UNITS  (WIN_FLOATS / 4)                   /* 4128 float4s */
#define LDS_UNITS  (WIN_UNITS + 8)                    /* +8 zero pad units */
#define NBLOCKS (B_ROWS * BLOCKS_PER_ROW)             /* 256 */

struct Coef { float g; float a1[4]; float a2[4]; };

__global__ __launch_bounds__(256) void cheby_decimate_kernel(
    const float* __restrict__ x, float* __restrict__ out, Coef c)
{
    __shared__ float4 lds[LDS_UNITS];
    const int t   = threadIdx.x;
    const int row = blockIdx.x / BLOCKS_PER_ROW;
    const int bc  = blockIdx.x % BLOCKS_PER_ROW;
    const float* __restrict__ xr = x + (size_t)row * T_LEN;
    const int wstart = bc * (TPB * L_CHUNK) - H_WARM;   // first float of window

    // ---- coalesced global -> LDS staging, XOR-swizzled on 16B units ----
    #pragma unroll
    for (int k = 0; k < (WIN_UNITS + TPB - 1) / TPB; ++k) {
        int w = t + TPB * k;
        if (w < WIN_UNITS) {
            int g = wstart + 4 * w;                     // aligned, mult of 4
            float4 v = make_float4(0.f, 0.f, 0.f, 0.f); // g<0: zero init state
            if (g >= 0) v = *reinterpret_cast<const float4*>(xr + g);
            lds[w ^ ((w >> 4) & 7)] = v;
        }
    }
    if (t < 8)  // zero the pad group (consumed only by discarded tail outputs)
        lds[WIN_UNITS + t] = make_float4(0.f, 0.f, 0.f, 0.f);
    __syncthreads();

    const float g0   = c.g;                    // b0 = b2 = g, b1 = 2g
    const float na10 = -c.a1[0], na20 = -c.a2[0];
    const float na11 = -c.a1[1], na21 = -c.a2[1];
    const float na12 = -c.a1[2], na22 = -c.a2[2];
    const float na13 = -c.a1[3], na23 = -c.a2[3];

    float z11=0.f,z12=0.f, z21=0.f,z22=0.f, z31=0.f,z32=0.f, z41=0.f,z42=0.f;
    float y1=0.f, y2=0.f, y3=0.f;   // pipeline delay regs (3 leading zeros)

#define LREAD(u) lds[(u) ^ (((u) >> 4) & 7)]
#define SEC(yin, z1, z2, na1, na2, oo) do {                                    \
        float w_ = g0 * (yin); oo = w_ + z1;                                   \
        z1 = fmaf(na1, oo, fmaf(2.f, w_, z2)); z2 = fmaf(na2, oo, w_);         \
    } while (0)
#define PSTEP(xi, STORE) do {                                                  \
        float o1, o2, o3, o4;                                                  \
        SEC((xi), z11, z12, na10, na20, o1);                                   \
        SEC(y1,   z21, z22, na11, na21, o2);                                   \
        SEC(y2,   z31, z32, na12, na22, o3);                                   \
        SEC(y3,   z41, z42, na13, na23, o4);                                   \
        y1 = o1; y2 = o2; y3 = o3; STORE;                                      \
    } while (0)

    // thread t: window floats [64t, 64t+192) = units [16t, 16t+48)
    const int ub = 16 * t;
    float4 cur = LREAD(ub);
    float outv[32];

    // warm-up: groups m=0..31 (samples 0..127 emerge; none live)
    #pragma unroll 4
    for (int m = 0; m < 32; ++m) {
        float4 nxt = LREAD(ub + m + 1);
        PSTEP(cur.x, (void)0); PSTEP(cur.y, (void)0);
        PSTEP(cur.z, (void)0); PSTEP(cur.w, (void)0);
        cur = nxt;
    }
    // live: groups m=32..48; o4 at i=4m+1 is sample 4m-2, at i=4m+3 sample 4m
    #pragma unroll
    for (int m = 32; m <= 48; ++m) {
        float4 nxt = (m < 48) ? LREAD(ub + m + 1)
                              : make_float4(0.f, 0.f, 0.f, 0.f);
        PSTEP(cur.x, (void)0);
        PSTEP(cur.y, if (m >= 33) outv[2*m - 65] = o4);
        PSTEP(cur.z, (void)0);
        PSTEP(cur.w, if (m <= 47) outv[2*m - 64] = o4);
        cur = nxt;
    }
#undef PSTEP
#undef SEC
#undef LREAD

    // ---- outputs -> LDS (swizzled) -> coalesced float4 stores ----
    __syncthreads();   // everyone done reading the staging buffer
    #pragma unroll
    for (int q = 0; q < 8; ++q) {   // unit o = 8t+q, swz within 8-group
        lds[8*t + (q ^ (t & 7))] =
            make_float4(outv[4*q], outv[4*q+1], outv[4*q+2], outv[4*q+3]);
    }
    __syncthreads();
    const size_t obase = (size_t)row * OUT_LEN + (size_t)bc * (TPB * L_CHUNK / 2);
    #pragma unroll
    for (int k = 0; k < 8; ++k) {
        int v = t + TPB * k;        // 2048 units total
        float4 d = lds[(v & ~7) + ((v & 7) ^ ((v >> 3) & 7))];
        *reinterpret_cast<float4*>(out + obase + 4 * v) = d;
    }
}

extern "C" void kernel_launch(void* const* d_in, const int* in_sizes, int n_in,
                              void* d_out, int out_size, void* d_ws, size_t ws_size,
                              hipStream_t stream)
{
    const float* x = (const float*)d_in[0];
    float* out = (float*)d_out;

    // cheby1(N=8, rp=0.05dB, Wn=0.5) SOS design in f64, exactly mirroring the
    // reference's math, then cast to f32 like jnp.asarray(..., float32).
    const int N = 8;
    const double rp = 0.05;
    const double eps = std::sqrt(std::pow(10.0, rp / 10.0) - 1.0);
    const double mu  = std::asinh(1.0 / eps) / N;

    std::complex<double> p[8];
    std::complex<double> prodnp(1.0, 0.0);
    for (int i = 0; i < N; ++i) {
        double theta = M_PI * (2.0 * (i + 1) - 1.0) / (2.0 * N);
        p[i] = std::complex<double>(-std::sinh(mu) * std::sin(theta),
                                     std::cosh(mu) * std::cos(theta));
        prodnp *= -p[i];
    }
    double gain = prodnp.real() / std::sqrt(1.0 + eps * eps);  // N even

    const double fs = 2.0;
    const double warped = 2.0 * fs * std::tan(M_PI * 0.5 / fs);  // = 4
    std::complex<double> prodden(1.0, 0.0);
    std::complex<double> pz[8];
    for (int i = 0; i < N; ++i) {
        p[i] *= warped;
        pz[i] = (2.0 * fs + p[i]) / (2.0 * fs - p[i]);
        prodden *= (2.0 * fs - p[i]);
    }
    gain *= std::pow(warped, (double)N);
    gain /= prodden.real();

    Coef c;
    int ns = 0;
    double A1[4], A2[4];
    for (int i = 0; i < N; ++i) {
        if (pz[i].imag() > 0.0) {
            A1[ns] = -2.0 * pz[i].real();
            A2[ns] = std::norm(pz[i]);
            ++ns;
        }
    }
    const double gsec = std::pow(gain, 1.0 / ns);
    c.g = (float)gsec;
    for (int s = 0; s < 4; ++s) { c.a1[s] = (float)A1[s]; c.a2[s] = (float)A2[s]; }

    dim3 block(TPB), grid(NBLOCKS);
    // DIAGNOSTIC: 8 identical launches per call (same work every call).
    // dur_us(8x) - dur_us(1x=71.5) = 7 * kernel_time.
    for (int rep = 0; rep < 8; ++rep) {
        hipLaunchKernelGGL(cheby_decimate_kernel, grid, block, 0, stream, x, out, c);
    }
}

// Round 10
// 72.055 us; speedup vs baseline: 2.1381x; 2.1381x over previous
//
#include <hip/hip_runtime.h>
#include <cmath>
#include <complex>

// ChebyDecimate: 8th-order Chebyshev-I lowpass (4 cascaded biquads, DF2T,
// zero init state) + decimate-by-2.  x: [32, 131072] f32 -> out: [32, 65536] f32.
//
// v5: overlap-save (H=128), sections software-pipelined AND packed 2-wide:
// sections (1,3) and (2,4) run as float2 lanes -> v_pk_fma_f32 etc.
// (gfx950 packed-FP32). Cross-feed is a register rename (i24 = o13_prev;
// i13 = {x_new, o24_prev.x}). Elementwise DAG identical to v3 => bit-identical.
// Input via LDS staging (XOR-swizzled, coalesced); outputs stored DIRECTLY
// (thread t owns 32 contiguous floats), no store transpose, one barrier total.
// Diagnostic (r9): kernel ~11.8us, harness fixed ~59.7us.

#define T_LEN   131072
#define B_ROWS  32
#define OUT_LEN (T_LEN / 2)
#define L_CHUNK 64
#define H_WARM  128
#define TPB     256
#define BLOCKS_PER_ROW (T_LEN / (L_CHUNK * TPB))      /* 8 */
#define WIN_FLOATS (TPB * L_CHUNK + H_WARM)           /* 16512 */
#define WIN_UNITS  (WIN_FLOATS / 4)                   /* 4128 float4s */
#define LDS_UNITS  (WIN_UNITS + 8)                    /* +8 zero pad units */
#define NBLOCKS (B_ROWS * BLOCKS_PER_ROW)             /* 256 */

typedef float v2f __attribute__((ext_vector_type(2)));

#if defined(__has_builtin)
# if __has_builtin(__builtin_elementwise_fma)
#  define FMA2(a, b, c) __builtin_elementwise_fma((a), (b), (c))
# endif
#endif
#ifndef FMA2
static __device__ __forceinline__ v2f fma2_(v2f a, v2f b, v2f c) {
    v2f r; r.x = fmaf(a.x, b.x, c.x); r.y = fmaf(a.y, b.y, c.y); return r;
}
# define FMA2 fma2_
#endif

struct Coef { float g; float a1[4]; float a2[4]; };

__global__ __launch_bounds__(256) void cheby_decimate_kernel(
    const float* __restrict__ x, float* __restrict__ out, Coef c)
{
    __shared__ float4 lds[LDS_UNITS];
    const int t   = threadIdx.x;
    const int row = blockIdx.x / BLOCKS_PER_ROW;
    const int bc  = blockIdx.x % BLOCKS_PER_ROW;
    const float* __restrict__ xr = x + (size_t)row * T_LEN;
    const int wstart = bc * (TPB * L_CHUNK) - H_WARM;   // first float of window

    // ---- coalesced global -> LDS staging, XOR-swizzled on 16B units ----
    #pragma unroll
    for (int k = 0; k < (WIN_UNITS + TPB - 1) / TPB; ++k) {
        int w = t + TPB * k;
        if (w < WIN_UNITS) {
            int g = wstart + 4 * w;                     // aligned, mult of 4
            float4 v = make_float4(0.f, 0.f, 0.f, 0.f); // g<0: zero init state
            if (g >= 0) v = *reinterpret_cast<const float4*>(xr + g);
            lds[w ^ ((w >> 4) & 7)] = v;
        }
    }
    if (t < 8)  // zero the pad group (consumed only by discarded tail outputs)
        lds[WIN_UNITS + t] = make_float4(0.f, 0.f, 0.f, 0.f);
    __syncthreads();

    // packed coefficients: pair A = sections (1,3), pair B = sections (2,4)
    const v2f gg   = { c.g, c.g };
    const v2f two  = { 2.f, 2.f };
    const v2f naA1 = { -c.a1[0], -c.a1[2] }, naA2 = { -c.a2[0], -c.a2[2] };
    const v2f naB1 = { -c.a1[1], -c.a1[3] }, naB2 = { -c.a2[1], -c.a2[3] };

    v2f zA1 = {0.f,0.f}, zA2 = {0.f,0.f}, zB1 = {0.f,0.f}, zB2 = {0.f,0.f};
    v2f o13 = {0.f,0.f}, o24 = {0.f,0.f};   // previous-step pair outputs

#define LREAD(u) lds[(u) ^ (((u) >> 4) & 7)]
    // one pipelined, packed step. Per step: 10 packed VALU + 1 insert.
    // o24.y is the section-4 output (sample i-3), identical DAG to v3.
#define PSTEP(xi, STORE) do {                                                  \
        v2f i13; i13.x = (xi); i13.y = o24.x;                                  \
        v2f i24 = o13;                                                         \
        v2f wA = gg * i13; v2f oA = wA + zA1; v2f tA = FMA2(two, wA, zA2);     \
        zA1 = FMA2(naA1, oA, tA); zA2 = FMA2(naA2, oA, wA);                    \
        v2f wB = gg * i24; v2f oB = wB + zB1; v2f tB = FMA2(two, wB, zB2);     \
        zB1 = FMA2(naB1, oB, tB); zB2 = FMA2(naB2, oB, wB);                    \
        o13 = oA; o24 = oB; STORE;                                             \
    } while (0)

    // thread t: window floats [64t, 64t+192) = units [16t, 16t+48)
    const int ub = 16 * t;
    float4 cur = LREAD(ub);
    float outv[32];

    // warm-up: groups m=0..31 (samples 0..127 emerge; none live)
    #pragma unroll 4
    for (int m = 0; m < 32; ++m) {
        float4 nxt = LREAD(ub + m + 1);
        PSTEP(cur.x, (void)0); PSTEP(cur.y, (void)0);
        PSTEP(cur.z, (void)0); PSTEP(cur.w, (void)0);
        cur = nxt;
    }
    // live: groups m=32..48; o4 at i=4m+1 is sample 4m-2, at i=4m+3 sample 4m
    #pragma unroll
    for (int m = 32; m <= 48; ++m) {
        float4 nxt = (m < 48) ? LREAD(ub + m + 1)
                              : make_float4(0.f, 0.f, 0.f, 0.f);
        PSTEP(cur.x, (void)0);
        PSTEP(cur.y, if (m >= 33) outv[2*m - 65] = o24.y);
        PSTEP(cur.z, (void)0);
        PSTEP(cur.w, if (m <= 47) outv[2*m - 64] = o24.y);
        cur = nxt;
    }
#undef PSTEP
#undef LREAD

    // ---- direct stores: thread t owns 32 contiguous output floats ----
    // L2 write-back merges the 128B each thread writes into full lines.
    float* __restrict__ op = out + (size_t)row * OUT_LEN
                                 + (size_t)bc * (TPB * L_CHUNK / 2) + 32 * t;
    #pragma unroll
    for (int q = 0; q < 8; ++q) {
        *reinterpret_cast<float4*>(op + 4 * q) =
            make_float4(outv[4*q], outv[4*q+1], outv[4*q+2], outv[4*q+3]);
    }
}

extern "C" void kernel_launch(void* const* d_in, const int* in_sizes, int n_in,
                              void* d_out, int out_size, void* d_ws, size_t ws_size,
                              hipStream_t stream)
{
    const float* x = (const float*)d_in[0];
    float* out = (float*)d_out;

    // cheby1(N=8, rp=0.05dB, Wn=0.5) SOS design in f64, exactly mirroring the
    // reference's math, then cast to f32 like jnp.asarray(..., float32).
    const int N = 8;
    const double rp = 0.05;
    const double eps = std::sqrt(std::pow(10.0, rp / 10.0) - 1.0);
    const double mu  = std::asinh(1.0 / eps) / N;

    std::complex<double> p[8];
    std::complex<double> prodnp(1.0, 0.0);
    for (int i = 0; i < N; ++i) {
        double theta = M_PI * (2.0 * (i + 1) - 1.0) / (2.0 * N);
        p[i] = std::complex<double>(-std::sinh(mu) * std::sin(theta),
                                     std::cosh(mu) * std::cos(theta));
        prodnp *= -p[i];
    }
    double gain = prodnp.real() / std::sqrt(1.0 + eps * eps);  // N even

    const double fs = 2.0;
    const double warped = 2.0 * fs * std::tan(M_PI * 0.5 / fs);  // = 4
    std::complex<double> prodden(1.0, 0.0);
    std::complex<double> pz[8];
    for (int i = 0; i < N; ++i) {
        p[i] *= warped;
        pz[i] = (2.0 * fs + p[i]) / (2.0 * fs - p[i]);
        prodden *= (2.0 * fs - p[i]);
    }
    gain *= std::pow(warped, (double)N);
    gain /= prodden.real();

    Coef c;
    int ns = 0;
    double A1[4], A2[4];
    for (int i = 0; i < N; ++i) {
        if (pz[i].imag() > 0.0) {
            A1[ns] = -2.0 * pz[i].real();
            A2[ns] = std::norm(pz[i]);
            ++ns;
        }
    }
    const double gsec = std::pow(gain, 1.0 / ns);
    c.g = (float)gsec;
    for (int s = 0; s < 4; ++s) { c.a1[s] = (float)A1[s]; c.a2[s] = (float)A2[s]; }

    dim3 block(TPB), grid(NBLOCKS);
    hipLaunchKernelGGL(cheby_decimate_kernel, grid, block, 0, stream, x, out, c);
}